// Round 2
// baseline (296.773 us; speedup 1.0000x reference)
//
#include <hip/hip_runtime.h>

typedef unsigned short u16;
typedef __attribute__((ext_vector_type(8))) short short8;    // 8 bf16 (4 VGPRs) — guide §3 verified type
typedef __attribute__((ext_vector_type(4))) float f32x4;
typedef __attribute__((ext_vector_type(4))) unsigned short u16x4;

typedef __attribute__((address_space(1))) void as1_void;
typedef __attribute__((address_space(3))) void as3_void;

// async global->LDS, 16B per lane; LDS dest = wave-uniform base + lane*16 (guide §5, m97/m104)
__device__ __forceinline__ void gld16(const u16* g, u16* l) {
  __builtin_amdgcn_global_load_lds((as1_void*)g, (as3_void*)l, 16, 0, 0);
}

__device__ __forceinline__ u16 f2bf(float f) {
  unsigned u = __float_as_uint(f);
  u += 0x7fffu + ((u >> 16) & 1u);   // RNE
  return (u16)(u >> 16);
}

// ---------------- fp32 -> bf16 ----------------
__global__ void cvt_bf16(const float* __restrict__ src, u16* __restrict__ dst, int n) {
  int i = blockIdx.x * 256 + threadIdx.x;
  if (i < n) dst[i] = f2bf(src[i]);
}

// ---------------- W_eff = W + 2 * up @ down, bf16 ----------------
// weff rows n: [0,768)=q  [768,1536)=k  [1536,2304)=v ; each row is K=768 contiguous
__global__ void prep_weff(const float* __restrict__ wq, const float* __restrict__ wk, const float* __restrict__ wv,
                          const float* __restrict__ dq, const float* __restrict__ uq,
                          const float* __restrict__ dk, const float* __restrict__ uk,
                          const float* __restrict__ dv, const float* __restrict__ uv,
                          u16* __restrict__ weff) {
  int idx = blockIdx.x * 256 + threadIdx.x;   // < 2304*768 exactly
  int n = idx / 768, d = idx - n * 768;
  const float *w, *dn, *up; int e;
  if (n < 768)       { w = wq; dn = dq; up = uq; e = n; }
  else if (n < 1536) { w = wk; dn = dk; up = uk; e = n - 768; }
  else               { w = wv; dn = dv; up = uv; e = n - 1536; }
  float acc = w[e * 768 + d];
  float lo = 0.f;
#pragma unroll
  for (int r = 0; r < 8; ++r) lo += up[e * 8 + r] * dn[r * 768 + d];
  weff[idx] = f2bf(acc + 2.0f * lo);   // SCALING = alpha/rank = 2
}

// ---------------- NT GEMM: C[m,n] = sum_k A[m,k]*B[n,k] (+bias) ----------------
// 128x128 block tile, BK=32, 4 waves in 2x2 of 64x64, 16x16x32 MFMA.
// LDS tiles are stored as XOR-swizzled 16B chunks: phys = row*4 + (g ^ ((row>>1)&3))
// mode 0: N=2304 -> q[h][s][64], k[h][s][64], vt[h][64][s] (bf16, +bq/bk/bv)
// mode 1: N=768  -> fo[s][768] fp32 (+bo)
__global__ __launch_bounds__(256) void gemm_nt(
    const u16* __restrict__ A, const u16* __restrict__ B, int K, int mode,
    const float* __restrict__ bq, const float* __restrict__ bk, const float* __restrict__ bv,
    u16* __restrict__ qo, u16* __restrict__ ko, u16* __restrict__ vto,
    const float* __restrict__ bo, float* __restrict__ fo) {
  __shared__ u16 As[128 * 32];
  __shared__ u16 Bs[128 * 32];
  const int tid = threadIdx.x;
  const int lane = tid & 63;
  const int wid = tid >> 6;
  const int qd = lane >> 4;      // quad 0..3
  const int m16 = lane & 15;
  const int wr = wid >> 1, wc = wid & 1;
  const int m0 = blockIdx.x * 128, n0 = blockIdx.y * 128;

  f32x4 acc[4][4];
#pragma unroll
  for (int i = 0; i < 4; ++i)
#pragma unroll
    for (int j = 0; j < 4; ++j)
#pragma unroll
      for (int e = 0; e < 4; ++e) acc[i][j][e] = 0.f;

  for (int k0 = 0; k0 < K; k0 += 32) {
    __syncthreads();
#pragma unroll
    for (int r = 0; r < 2; ++r) {
      int p = r * 256 + tid;                 // chunk index 0..511
      int row = p >> 2;
      int g = (p & 3) ^ ((row >> 1) & 3);    // logical 8-elt group stored at phys chunk p
      gld16(A + (size_t)(m0 + row) * K + k0 + g * 8, &As[(p - lane) * 8]);
      gld16(B + (size_t)(n0 + row) * K + k0 + g * 8, &Bs[(p - lane) * 8]);
    }
    __syncthreads();
    short8 af[4], bf[4];
#pragma unroll
    for (int i = 0; i < 4; ++i) {
      int ar = wr * 64 + i * 16 + m16;
      af[i] = *(const short8*)&As[(ar * 4 + (qd ^ ((ar >> 1) & 3))) * 8];
      int br = wc * 64 + i * 16 + m16;
      bf[i] = *(const short8*)&Bs[(br * 4 + (qd ^ ((br >> 1) & 3))) * 8];
    }
#pragma unroll
    for (int i = 0; i < 4; ++i)
#pragma unroll
      for (int j = 0; j < 4; ++j)
        acc[i][j] = __builtin_amdgcn_mfma_f32_16x16x32_bf16(af[i], bf[j], acc[i][j], 0, 0, 0);
  }

  // epilogue: C/D layout col = m16, row = qd*4 + reg (m89/m91-verified)
#pragma unroll
  for (int i = 0; i < 4; ++i) {
    int gr = m0 + wr * 64 + i * 16 + qd * 4;
#pragma unroll
    for (int j = 0; j < 4; ++j) {
      int gc = n0 + wc * 64 + j * 16 + m16;
      if (mode == 0) {
        if (gc < 768) {
          float bias = bq[gc];
          int h = gc >> 6, d = gc & 63;
#pragma unroll
          for (int r = 0; r < 4; ++r)
            qo[((size_t)h * 4096 + gr + r) * 64 + d] = f2bf(acc[i][j][r] + bias);
        } else if (gc < 1536) {
          int c = gc - 768;
          float bias = bk[c];
          int h = c >> 6, d = c & 63;
#pragma unroll
          for (int r = 0; r < 4; ++r)
            ko[((size_t)h * 4096 + gr + r) * 64 + d] = f2bf(acc[i][j][r] + bias);
        } else {
          int c = gc - 1536;
          float bias = bv[c];
          int h = c >> 6, d = c & 63;
          u16x4 pk;
#pragma unroll
          for (int r = 0; r < 4; ++r) pk[r] = f2bf(acc[i][j][r] + bias);
          *(u16x4*)&vto[((size_t)h * 64 + d) * 4096 + gr] = pk;   // s contiguous
        }
      } else {
        float bias = bo[gc];
#pragma unroll
        for (int r = 0; r < 4; ++r)
          fo[(size_t)(gr + r) * 768 + gc] = acc[i][j][r] + bias;
      }
    }
  }
}

// ---------------- flash attention fwd ----------------
// grid (64 qtiles, 12 heads), 256 thr. Wave w owns q-rows [s0+16w, s0+16w+16).
// K tile 128x64 LDS (swizzle: phys = row*8 + (g ^ (row&7)))
// V^T tile 64x128 LDS (swizzle: phys = d*16 + (g ^ (d&15)))
// P round-trips through wave-private LDS [16][136] (pad +8 bf16 breaks read conflicts)
__global__ __launch_bounds__(256) void attn_fwd(
    const u16* __restrict__ Q, const u16* __restrict__ Kg, const u16* __restrict__ Vt,
    u16* __restrict__ out) {
  __shared__ u16 Ks[128 * 64];
  __shared__ u16 Vs[64 * 128];
  __shared__ u16 Ps[4 * 16 * 136];
  const int tid = threadIdx.x, lane = tid & 63, wid = tid >> 6;
  const int qd = lane >> 4, m16 = lane & 15;
  const int h = blockIdx.y;
  const int s0 = blockIdx.x * 64;
  const int qrow = s0 + wid * 16;

  const u16* qb = Q + ((size_t)h * 4096 + qrow + m16) * 64;
  short8 qf[2];
  qf[0] = *(const short8*)(qb + qd * 8);
  qf[1] = *(const short8*)(qb + 32 + qd * 8);

  float mrun[4], lrun[4];
  f32x4 oacc[4];
#pragma unroll
  for (int r = 0; r < 4; ++r) { mrun[r] = -1e30f; lrun[r] = 0.f; }
#pragma unroll
  for (int d = 0; d < 4; ++d)
#pragma unroll
    for (int r = 0; r < 4; ++r) oacc[d][r] = 0.f;

  u16* pw = &Ps[wid * 16 * 136];

  for (int kt = 0; kt < 4096; kt += 128) {
    __syncthreads();                          // prev PV reads done before restage
#pragma unroll
    for (int rr = 0; rr < 4; ++rr) {
      int p = rr * 256 + tid;                 // 0..1023 chunks for each tile
      int krow = p >> 3;
      int kg = (p & 7) ^ (krow & 7);
      gld16(Kg + ((size_t)h * 4096 + kt + krow) * 64 + kg * 8, &Ks[(p - lane) * 8]);
      int vd = p >> 4;
      int vg = (p & 15) ^ (vd & 15);
      gld16(Vt + ((size_t)h * 64 + vd) * 4096 + kt + vg * 8, &Vs[(p - lane) * 8]);
    }
    __syncthreads();

    // scores S = Q K^T / 8 : wave computes 16 rows x 128 cols
    f32x4 sacc[8];
#pragma unroll
    for (int c = 0; c < 8; ++c)
#pragma unroll
      for (int r = 0; r < 4; ++r) sacc[c][r] = 0.f;
#pragma unroll
    for (int ks = 0; ks < 2; ++ks) {
#pragma unroll
      for (int c = 0; c < 8; ++c) {
        int kr = c * 16 + m16;
        int g = ks * 4 + qd;
        short8 bfr = *(const short8*)&Ks[(kr * 8 + (g ^ (kr & 7))) * 8];
        sacc[c] = __builtin_amdgcn_mfma_f32_16x16x32_bf16(qf[ks], bfr, sacc[c], 0, 0, 0);
      }
    }
    // online softmax (rows live in the quad's 16 lanes)
    float al[4];
#pragma unroll
    for (int r = 0; r < 4; ++r) {
      float mx = -1e30f;
#pragma unroll
      for (int c = 0; c < 8; ++c) { sacc[c][r] *= 0.125f; mx = fmaxf(mx, sacc[c][r]); }
#pragma unroll
      for (int off = 1; off < 16; off <<= 1) mx = fmaxf(mx, __shfl_xor(mx, off));
      float mnew = fmaxf(mrun[r], mx);
      al[r] = __expf(mrun[r] - mnew);
      mrun[r] = mnew;
      float s = 0.f;
#pragma unroll
      for (int c = 0; c < 8; ++c) {
        float p_ = __expf(sacc[c][r] - mnew);
        sacc[c][r] = p_;
        s += p_;
      }
#pragma unroll
      for (int off = 1; off < 16; off <<= 1) s += __shfl_xor(s, off);
      lrun[r] = lrun[r] * al[r] + s;
    }
#pragma unroll
    for (int d = 0; d < 4; ++d)
#pragma unroll
      for (int r = 0; r < 4; ++r) oacc[d][r] *= al[r];
    // P -> LDS (C-layout rows qd*4+r) for A-operand re-read
#pragma unroll
    for (int c = 0; c < 8; ++c)
#pragma unroll
      for (int r = 0; r < 4; ++r)
        pw[(qd * 4 + r) * 136 + c * 16 + m16] = f2bf(sacc[c][r]);
    __syncthreads();                          // P visible wave-wide
    // O += P V : A = P[16x128] from LDS, B = V[k][d] = Vt[d][k]
#pragma unroll
    for (int ks = 0; ks < 4; ++ks) {
      short8 pf = *(const short8*)&pw[m16 * 136 + ks * 32 + qd * 8];
#pragma unroll
      for (int d = 0; d < 4; ++d) {
        int vr = d * 16 + m16;
        int g = ks * 4 + qd;
        short8 vfr = *(const short8*)&Vs[(vr * 16 + (g ^ (vr & 15))) * 8];
        oacc[d] = __builtin_amdgcn_mfma_f32_16x16x32_bf16(pf, vfr, oacc[d], 0, 0, 0);
      }
    }
  }
  // epilogue: row = qrow + qd*4 + r, col = h*64 + d*16 + m16
  float inv[4];
#pragma unroll
  for (int r = 0; r < 4; ++r) inv[r] = 1.0f / lrun[r];
#pragma unroll
  for (int d = 0; d < 4; ++d)
#pragma unroll
    for (int r = 0; r < 4; ++r)
      out[(size_t)(qrow + qd * 4 + r) * 768 + h * 64 + d * 16 + m16] = f2bf(oacc[d][r] * inv[r]);
}

extern "C" void kernel_launch(void* const* d_in, const int* in_sizes, int n_in,
                              void* d_out, int out_size, void* d_ws, size_t ws_size,
                              hipStream_t stream) {
  const float* x   = (const float*)d_in[0];
  const float* wq  = (const float*)d_in[1];
  const float* bq  = (const float*)d_in[2];
  const float* wk  = (const float*)d_in[3];
  const float* bk  = (const float*)d_in[4];
  const float* wv  = (const float*)d_in[5];
  const float* bv  = (const float*)d_in[6];
  const float* wo  = (const float*)d_in[7];
  const float* bo  = (const float*)d_in[8];
  const float* dq  = (const float*)d_in[9];
  const float* uq  = (const float*)d_in[10];
  const float* dk  = (const float*)d_in[11];
  const float* uk  = (const float*)d_in[12];
  const float* dv  = (const float*)d_in[13];
  const float* uv  = (const float*)d_in[14];
  float* out = (float*)d_out;

  char* ws = (char*)d_ws;
  u16* xb   = (u16*)(ws);                 // 4096*768        bf16  (6291456 B)
  u16* weff = (u16*)(ws + 6291456);       // 2304*768
  u16* wob  = (u16*)(ws + 9830400);       // 768*768
  u16* qb   = (u16*)(ws + 11010048);      // [12][4096][64]
  u16* kb   = (u16*)(ws + 17301504);      // [12][4096][64]
  u16* vtb  = (u16*)(ws + 23592960);      // [12][64][4096]
  u16* ab   = (u16*)(ws + 29884416);      // [4096][768]     (ends 36175872 B)

  cvt_bf16<<<12288, 256, 0, stream>>>(x, xb, 4096 * 768);
  cvt_bf16<<<2304, 256, 0, stream>>>(wo, wob, 768 * 768);
  prep_weff<<<6912, 256, 0, stream>>>(wq, wk, wv, dq, uq, dk, uk, dv, uv, weff);
  gemm_nt<<<dim3(32, 18), 256, 0, stream>>>(xb, weff, 768, 0, bq, bk, bv, qb, kb, vtb,
                                            nullptr, nullptr);
  attn_fwd<<<dim3(64, 12), 256, 0, stream>>>(qb, kb, vtb, ab);
  gemm_nt<<<dim3(32, 6), 256, 0, stream>>>(ab, wob, 768, 1, nullptr, nullptr, nullptr,
                                           nullptr, nullptr, nullptr, bo, out);
}

// Round 3
// 253.696 us; speedup vs baseline: 1.1698x; 1.1698x over previous
//
#include <hip/hip_runtime.h>

typedef unsigned short u16;
typedef __attribute__((ext_vector_type(8))) short short8;    // 8 bf16 (4 VGPRs)
typedef __attribute__((ext_vector_type(4))) float f32x4;
typedef __attribute__((ext_vector_type(4))) unsigned short u16x4;

typedef __attribute__((address_space(1))) void as1_void;
typedef __attribute__((address_space(3))) void as3_void;

// async global->LDS, 16B per lane; LDS dest = wave-uniform base + lane*16
__device__ __forceinline__ void gld16(const u16* g, u16* l) {
  __builtin_amdgcn_global_load_lds((as1_void*)g, (as3_void*)l, 16, 0, 0);
}

__device__ __forceinline__ u16 f2bf(float f) {
  unsigned u = __float_as_uint(f);
  u += 0x7fffu + ((u >> 16) & 1u);   // RNE
  return (u16)(u >> 16);
}

// ---------------- fp32 -> bf16 ----------------
__global__ void cvt_bf16(const float* __restrict__ src, u16* __restrict__ dst, int n) {
  int i = blockIdx.x * 256 + threadIdx.x;
  if (i < n) dst[i] = f2bf(src[i]);
}

// ---------------- W_eff = W + 2 * up @ down, bf16 ----------------
__global__ void prep_weff(const float* __restrict__ wq, const float* __restrict__ wk, const float* __restrict__ wv,
                          const float* __restrict__ dq, const float* __restrict__ uq,
                          const float* __restrict__ dk, const float* __restrict__ uk,
                          const float* __restrict__ dv, const float* __restrict__ uv,
                          u16* __restrict__ weff) {
  int idx = blockIdx.x * 256 + threadIdx.x;   // < 2304*768 exactly
  int n = idx / 768, d = idx - n * 768;
  const float *w, *dn, *up; int e;
  if (n < 768)       { w = wq; dn = dq; up = uq; e = n; }
  else if (n < 1536) { w = wk; dn = dk; up = uk; e = n - 768; }
  else               { w = wv; dn = dv; up = uv; e = n - 1536; }
  float acc = w[e * 768 + d];
  float lo = 0.f;
#pragma unroll
  for (int r = 0; r < 8; ++r) lo += up[e * 8 + r] * dn[r * 768 + d];
  weff[idx] = f2bf(acc + 2.0f * lo);   // SCALING = alpha/rank = 2
}

// ---------------- NT GEMM: C[m,n] = sum_k A[m,k]*B[n,k] (+bias) ----------------
// 128x128 block tile, BK=32, 4 waves in 2x2 of 64x64, 16x16x32 MFMA.
// mode 0: N=2304 -> q[h][s][64] (pre-scaled by 0.125*log2e), k[h][s][64], vt[h][64][s]
// mode 1: N=768  -> fo[s][768] fp32 (+bo)
__global__ __launch_bounds__(256) void gemm_nt(
    const u16* __restrict__ A, const u16* __restrict__ B, int K, int mode,
    const float* __restrict__ bq, const float* __restrict__ bk, const float* __restrict__ bv,
    u16* __restrict__ qo, u16* __restrict__ ko, u16* __restrict__ vto,
    const float* __restrict__ bo, float* __restrict__ fo) {
  __shared__ u16 As[128 * 32];
  __shared__ u16 Bs[128 * 32];
  const int tid = threadIdx.x;
  const int lane = tid & 63;
  const int wid = tid >> 6;
  const int qd = lane >> 4;
  const int m16 = lane & 15;
  const int wr = wid >> 1, wc = wid & 1;
  const int m0 = blockIdx.x * 128, n0 = blockIdx.y * 128;

  f32x4 acc[4][4];
#pragma unroll
  for (int i = 0; i < 4; ++i)
#pragma unroll
    for (int j = 0; j < 4; ++j)
#pragma unroll
      for (int e = 0; e < 4; ++e) acc[i][j][e] = 0.f;

  for (int k0 = 0; k0 < K; k0 += 32) {
    __syncthreads();
#pragma unroll
    for (int r = 0; r < 2; ++r) {
      int p = r * 256 + tid;
      int row = p >> 2;
      int g = (p & 3) ^ ((row >> 1) & 3);
      gld16(A + (size_t)(m0 + row) * K + k0 + g * 8, &As[(p - lane) * 8]);
      gld16(B + (size_t)(n0 + row) * K + k0 + g * 8, &Bs[(p - lane) * 8]);
    }
    __syncthreads();
    short8 af[4], bf[4];
#pragma unroll
    for (int i = 0; i < 4; ++i) {
      int ar = wr * 64 + i * 16 + m16;
      af[i] = *(const short8*)&As[(ar * 4 + (qd ^ ((ar >> 1) & 3))) * 8];
      int br = wc * 64 + i * 16 + m16;
      bf[i] = *(const short8*)&Bs[(br * 4 + (qd ^ ((br >> 1) & 3))) * 8];
    }
#pragma unroll
    for (int i = 0; i < 4; ++i)
#pragma unroll
      for (int j = 0; j < 4; ++j)
        acc[i][j] = __builtin_amdgcn_mfma_f32_16x16x32_bf16(af[i], bf[j], acc[i][j], 0, 0, 0);
  }

  // C/D layout: col = m16, row = qd*4 + reg
#pragma unroll
  for (int i = 0; i < 4; ++i) {
    int gr = m0 + wr * 64 + i * 16 + qd * 4;
#pragma unroll
    for (int j = 0; j < 4; ++j) {
      int gc = n0 + wc * 64 + j * 16 + m16;
      if (mode == 0) {
        if (gc < 768) {
          float bias = bq[gc];
          int h = gc >> 6, d = gc & 63;
          // fold attention scale 1/8 and log2(e) into Q: exp(x/8) = exp2(x*0.18034)
#pragma unroll
          for (int r = 0; r < 4; ++r)
            qo[((size_t)h * 4096 + gr + r) * 64 + d] = f2bf((acc[i][j][r] + bias) * 0.18033688f);
        } else if (gc < 1536) {
          int c = gc - 768;
          float bias = bk[c];
          int h = c >> 6, d = c & 63;
#pragma unroll
          for (int r = 0; r < 4; ++r)
            ko[((size_t)h * 4096 + gr + r) * 64 + d] = f2bf(acc[i][j][r] + bias);
        } else {
          int c = gc - 1536;
          float bias = bv[c];
          int h = c >> 6, d = c & 63;
          u16x4 pk;
#pragma unroll
          for (int r = 0; r < 4; ++r) pk[r] = f2bf(acc[i][j][r] + bias);
          *(u16x4*)&vto[((size_t)h * 64 + d) * 4096 + gr] = pk;
        }
      } else {
        float bias = bo[gc];
#pragma unroll
        for (int r = 0; r < 4; ++r)
          fo[(size_t)(gr + r) * 768 + gc] = acc[i][j][r] + bias;
      }
    }
  }
}

// ---------------- flash attention fwd (S^T form, fixed-max base-2 softmax) ----------------
// grid (32 qtiles, 12 heads, kspl), 256 thr. Wave w owns 32 q-rows (2 MFMA tiles).
// S^T = mfma(Kfrag, Qfrag): lane(qd,m16) holds S[q=m16][k=c*16+qd*4+r] -> per-lane softmax.
// P LDS: per (wave,tile) 16x128 region, XOR-swizzled 16B chunks: phys = q*16 + (kc ^ q).
// LDS = 16K (Ks) + 16K (Vs) + 32K (Ps) = 64 KB exactly -> 2 blocks/CU.
__global__ __launch_bounds__(256) void attn_fwd(
    const u16* __restrict__ Q, const u16* __restrict__ Kg, const u16* __restrict__ Vt,
    float* __restrict__ Opart, float* __restrict__ lpart, u16* __restrict__ abo, int kspl) {
  __shared__ u16 Ks[128 * 64];
  __shared__ u16 Vs[64 * 128];
  __shared__ u16 Ps[8 * 16 * 128];
  const int tid = threadIdx.x, lane = tid & 63, wid = tid >> 6;
  const int qd = lane >> 4, m16 = lane & 15;
  const int h = blockIdx.y;
  const int qrow = blockIdx.x * 128 + wid * 32;
  const int kbase = blockIdx.z * (4096 / kspl);
  const int niter = (4096 / kspl) >> 7;

  short8 qf[2][2];
#pragma unroll
  for (int t = 0; t < 2; ++t) {
    const u16* qb = Q + ((size_t)h * 4096 + qrow + t * 16 + m16) * 64;
#pragma unroll
    for (int ks = 0; ks < 2; ++ks) qf[t][ks] = *(const short8*)(qb + ks * 32 + qd * 8);
  }

  float lrun[2] = {0.f, 0.f};
  f32x4 oacc[2][4];
#pragma unroll
  for (int t = 0; t < 2; ++t)
#pragma unroll
    for (int d = 0; d < 4; ++d)
#pragma unroll
      for (int r = 0; r < 4; ++r) oacc[t][d][r] = 0.f;

  for (int it = 0; it < niter; ++it) {
    const int kt = kbase + it * 128;
    __syncthreads();                          // prev frag reads done before restage
#pragma unroll
    for (int rr = 0; rr < 4; ++rr) {
      int p = rr * 256 + tid;
      int krow = p >> 3;
      int kg = (p & 7) ^ (krow & 7);
      gld16(Kg + ((size_t)h * 4096 + kt + krow) * 64 + kg * 8, &Ks[(p - lane) * 8]);
      int vd = p >> 4;
      int vg = (p & 15) ^ (vd & 15);
      gld16(Vt + ((size_t)h * 64 + vd) * 4096 + kt + vg * 8, &Vs[(p - lane) * 8]);
    }
    __syncthreads();

    // S^T: K-frags read once, shared by both q-tiles
    f32x4 sacc[2][8];
#pragma unroll
    for (int t = 0; t < 2; ++t)
#pragma unroll
      for (int c = 0; c < 8; ++c)
#pragma unroll
        for (int r = 0; r < 4; ++r) sacc[t][c][r] = 0.f;
#pragma unroll
    for (int ks = 0; ks < 2; ++ks) {
#pragma unroll
      for (int c = 0; c < 8; ++c) {
        int kr = c * 16 + m16;
        int g = ks * 4 + qd;
        short8 kf = *(const short8*)&Ks[(kr * 8 + (g ^ (kr & 7))) * 8];
        sacc[0][c] = __builtin_amdgcn_mfma_f32_16x16x32_bf16(kf, qf[0][ks], sacc[0][c], 0, 0, 0);
        sacc[1][c] = __builtin_amdgcn_mfma_f32_16x16x32_bf16(kf, qf[1][ks], sacc[1][c], 0, 0, 0);
      }
    }
    // per-lane softmax (scores pre-scaled to log2 domain; fixed max), pack P half-up
#pragma unroll
    for (int t = 0; t < 2; ++t) {
      const int pbase = (wid * 2 + t) * 2048;
      float lp = 0.f;
#pragma unroll
      for (int c = 0; c < 8; ++c) {
        u16x4 pk;
#pragma unroll
        for (int r = 0; r < 4; ++r) {
          float p = __builtin_amdgcn_exp2f(sacc[t][c][r]);
          lp += p;
          pk[r] = (u16)((__float_as_uint(p) + 0x8000u) >> 16);
        }
        int kc = 2 * c + (qd >> 1);          // 8-elem chunk of k-row, half written per qd parity
        *(u16x4*)&Ps[pbase + m16 * 128 + ((kc ^ m16) << 3) + ((qd & 1) << 2)] = pk;
      }
      lrun[t] += lp;
    }
    // O += P V  (wave-private P: no barrier needed, lgkmcnt orders write->read)
#pragma unroll
    for (int ks = 0; ks < 4; ++ks) {
      int kc2 = ks * 4 + qd;
      short8 pf0 = *(const short8*)&Ps[(wid * 2 + 0) * 2048 + m16 * 128 + ((kc2 ^ m16) << 3)];
      short8 pf1 = *(const short8*)&Ps[(wid * 2 + 1) * 2048 + m16 * 128 + ((kc2 ^ m16) << 3)];
#pragma unroll
      for (int d = 0; d < 4; ++d) {
        int vr = d * 16 + m16;
        int g = ks * 4 + qd;
        short8 vf = *(const short8*)&Vs[(vr * 16 + (g ^ (vr & 15))) * 8];
        oacc[0][d] = __builtin_amdgcn_mfma_f32_16x16x32_bf16(pf0, vf, oacc[0][d], 0, 0, 0);
        oacc[1][d] = __builtin_amdgcn_mfma_f32_16x16x32_bf16(pf1, vf, oacc[1][d], 0, 0, 0);
      }
    }
  }

  // l: reduce across the 4 quads (once per kernel, not per iter)
#pragma unroll
  for (int t = 0; t < 2; ++t) {
    lrun[t] += __shfl_xor(lrun[t], 16);
    lrun[t] += __shfl_xor(lrun[t], 32);
  }

  if (kspl == 2) {
    // unnormalized partials (fixed-max => partials are directly summable)
#pragma unroll
    for (int t = 0; t < 2; ++t)
      if (lane < 16)
        lpart[((size_t)blockIdx.z * 4096 + qrow + t * 16 + m16) * 12 + h] = lrun[t];
    float* ob = Opart + (size_t)blockIdx.z * 4096 * 768;
#pragma unroll
    for (int t = 0; t < 2; ++t)
#pragma unroll
      for (int d = 0; d < 4; ++d)
#pragma unroll
        for (int r = 0; r < 4; ++r)
          ob[(size_t)(qrow + t * 16 + qd * 4 + r) * 768 + h * 64 + d * 16 + m16] = oacc[t][d][r];
  } else {
    // single-pass: normalize and write bf16 directly
#pragma unroll
    for (int t = 0; t < 2; ++t) {
      float li[4];
#pragma unroll
      for (int r = 0; r < 4; ++r) li[r] = 1.0f / __shfl(lrun[t], qd * 4 + r);
#pragma unroll
      for (int d = 0; d < 4; ++d)
#pragma unroll
        for (int r = 0; r < 4; ++r)
          abo[(size_t)(qrow + t * 16 + qd * 4 + r) * 768 + h * 64 + d * 16 + m16] =
              f2bf(oacc[t][d][r] * li[r]);
    }
  }
}

// ---------------- merge the 2 k-split partials + normalize -> bf16 ----------------
__global__ void merge_norm(const float* __restrict__ Opart, const float* __restrict__ lpart,
                           u16* __restrict__ abo) {
  int idx = blockIdx.x * 256 + threadIdx.x;   // 4096*768 exactly
  int s = idx / 768, c = idx - s * 768;
  int h = c >> 6;
  float o = Opart[idx] + Opart[4096 * 768 + idx];
  float l = lpart[s * 12 + h] + lpart[(4096 + s) * 12 + h];
  abo[idx] = f2bf(o / l);
}

extern "C" void kernel_launch(void* const* d_in, const int* in_sizes, int n_in,
                              void* d_out, int out_size, void* d_ws, size_t ws_size,
                              hipStream_t stream) {
  const float* x   = (const float*)d_in[0];
  const float* wq  = (const float*)d_in[1];
  const float* bq  = (const float*)d_in[2];
  const float* wk  = (const float*)d_in[3];
  const float* bk  = (const float*)d_in[4];
  const float* wv  = (const float*)d_in[5];
  const float* bv  = (const float*)d_in[6];
  const float* wo  = (const float*)d_in[7];
  const float* bo  = (const float*)d_in[8];
  const float* dq  = (const float*)d_in[9];
  const float* uq  = (const float*)d_in[10];
  const float* dk  = (const float*)d_in[11];
  const float* uk  = (const float*)d_in[12];
  const float* dv  = (const float*)d_in[13];
  const float* uv  = (const float*)d_in[14];
  float* out = (float*)d_out;

  char* ws = (char*)d_ws;
  u16* xb    = (u16*)(ws);                 // 4096*768 bf16 (6291456 B); dead after QKV gemm
  u16* ab    = (u16*)(ws);                 // aliases xb: attn output [4096][768] bf16
  u16* weff  = (u16*)(ws + 6291456);       // 2304*768
  u16* wob   = (u16*)(ws + 9830400);       // 768*768
  u16* qb    = (u16*)(ws + 11010048);      // [12][4096][64]
  u16* kb    = (u16*)(ws + 17301504);      // [12][4096][64]
  u16* vtb   = (u16*)(ws + 23592960);      // [12][64][4096]
  float* Op  = (float*)(ws + 29884416);    // [2][4096][768] f32 (25165824 B)
  float* lp  = (float*)(ws + 55050240);    // [2][4096][12]  f32 (393216 B) -> end 55443456

  const int kspl = (ws_size >= 55443456ull) ? 2 : 1;

  cvt_bf16<<<12288, 256, 0, stream>>>(x, xb, 4096 * 768);
  cvt_bf16<<<2304, 256, 0, stream>>>(wo, wob, 768 * 768);
  prep_weff<<<6912, 256, 0, stream>>>(wq, wk, wv, dq, uq, dk, uk, dv, uv, weff);
  gemm_nt<<<dim3(32, 18), 256, 0, stream>>>(xb, weff, 768, 0, bq, bk, bv, qb, kb, vtb,
                                            nullptr, nullptr);
  attn_fwd<<<dim3(32, 12, kspl), 256, 0, stream>>>(qb, kb, vtb, Op, lp, ab, kspl);
  if (kspl == 2) merge_norm<<<12288, 256, 0, stream>>>(Op, lp, ab);
  gemm_nt<<<dim3(32, 6), 256, 0, stream>>>(ab, wob, 768, 1, nullptr, nullptr, nullptr,
                                           nullptr, nullptr, nullptr, bo, out);
}